// Round 5
// baseline (617.943 us; speedup 1.0000x reference)
//
#include <hip/hip_runtime.h>

#define D_IN  4096
#define D_OUT 4096
#define RANK  256
#define KCAT  (D_IN + RANK)   // 4352

typedef _Float16 h8 __attribute__((ext_vector_type(8)));
typedef float    f4 __attribute__((ext_vector_type(4)));
typedef float    f16v __attribute__((ext_vector_type(16)));

__device__ __forceinline__ void gload16(const void* g, void* l) {
  __builtin_amdgcn_global_load_lds(
      (const __attribute__((address_space(1))) void*)g,
      (__attribute__((address_space(3))) void*)l, 16, 0, 0);
}

__device__ __forceinline__ h8 dq8(int4 v0, int4 v1, float s) {
  h8 h;
  h[0] = (_Float16)((float)v0.x * s);
  h[1] = (_Float16)((float)v0.y * s);
  h[2] = (_Float16)((float)v0.z * s);
  h[3] = (_Float16)((float)v0.w * s);
  h[4] = (_Float16)((float)v1.x * s);
  h[5] = (_Float16)((float)v1.y * s);
  h[6] = (_Float16)((float)v1.z * s);
  h[7] = (_Float16)((float)v1.w * s);
  return h;
}

// ---------------- prologue: dequant + pack (all exact-fit, 16B stores) -------

// q part: W[row][0:4096) ; total threads = D_OUT * 512
__global__ __launch_bounds__(256) void k_dequant_q(
    const int* __restrict__ qv, const float* __restrict__ qs,
    _Float16* __restrict__ W) {
  int i = blockIdx.x * 256 + threadIdx.x;
  int row = i >> 9, c8 = (i & 511) << 3;
  const int* p = qv + (size_t)row * D_IN + c8;
  int4 v0 = *(const int4*)p, v1 = *(const int4*)(p + 4);
  float s = qs[row * (D_IN / 128) + (c8 >> 7)];
  *(h8*)(W + (size_t)row * KCAT + c8) = dq8(v0, v1, s);
}

// l part: W[row][4096:4352) ; total threads = D_OUT * 32
__global__ __launch_bounds__(256) void k_dequant_l(
    const int* __restrict__ lv, const float* __restrict__ ls,
    _Float16* __restrict__ W) {
  int i = blockIdx.x * 256 + threadIdx.x;
  int row = i >> 5, c8 = (i & 31) << 3;
  const int* p = lv + (size_t)row * RANK + c8;
  int4 v0 = *(const int4*)p, v1 = *(const int4*)(p + 4);
  float s = ls[row * (RANK / 128) + (c8 >> 7)];
  *(h8*)(W + (size_t)row * KCAT + D_IN + c8) = dq8(v0, v1, s);
}

// r: total threads = RANK * 512
__global__ __launch_bounds__(256) void k_dequant_r(
    const int* __restrict__ rv, const float* __restrict__ rs,
    _Float16* __restrict__ R) {
  int i = blockIdx.x * 256 + threadIdx.x;
  int row = i >> 9, c8 = (i & 511) << 3;
  const int* p = rv + (size_t)row * D_IN + c8;
  int4 v0 = *(const int4*)p, v1 = *(const int4*)(p + 4);
  float s = rs[row * (D_IN / 128) + (c8 >> 7)];
  *(h8*)(R + (size_t)row * D_IN + c8) = dq8(v0, v1, s);
}

// x f32 -> f16 into Xcat[:, 0:4096) ; total threads = M * 512
__global__ __launch_bounds__(256) void k_convert_x(
    const float* __restrict__ x, _Float16* __restrict__ X) {
  int i = blockIdx.x * 256 + threadIdx.x;
  int row = i >> 9, c8 = (i & 511) << 3;
  const float* p = x + (size_t)row * D_IN + c8;
  f4 v0 = *(const f4*)p, v1 = *(const f4*)(p + 4);
  h8 h;
  h[0] = (_Float16)v0[0]; h[1] = (_Float16)v0[1];
  h[2] = (_Float16)v0[2]; h[3] = (_Float16)v0[3];
  h[4] = (_Float16)v1[0]; h[5] = (_Float16)v1[1];
  h[6] = (_Float16)v1[2]; h[7] = (_Float16)v1[3];
  *(h8*)(X + (size_t)row * KCAT + c8) = h;
}

// ---------------- small GEMM (xr path): m97 structure, 64^2 ----------------
template<int BM, int BN, int MF, int NF, bool OUT_F16, bool ADD_BIAS>
__global__ __launch_bounds__(256) void k_gemm_bt(
    const _Float16* __restrict__ A, int lda,
    const _Float16* __restrict__ B, int ldb,
    void* __restrict__ Cv, int ldc,
    const float* __restrict__ bias,
    int K, int grid_n) {
  constexpr int WM = MF * 16, WN = NF * 16;
  __shared__ _Float16 As[BM][32];
  __shared__ _Float16 Bs[BN][32];

  int bid = blockIdx.x;
  { int q = gridDim.x >> 3; bid = (bid & 7) * q + (bid >> 3); }
  int bm = bid / grid_n, bn = bid % grid_n;

  int tid  = threadIdx.x;
  int lane = tid & 63, wave = tid >> 6;
  int wr = wave >> 1, wc = wave & 1;

  int trow = tid >> 2;
  int tcol = (tid & 3) * 8;
  const _Float16* ga = A + (size_t)(bm * BM + trow) * lda + tcol;
  const _Float16* gb = B + (size_t)(bn * BN + trow) * ldb + tcol;

  f4 acc[MF][NF] = {};

  int fr = lane & 15;
  int fk = (lane >> 4) * 8;

  for (int k0 = 0; k0 < K; k0 += 32) {
#pragma unroll
    for (int p = 0; p < BM / 64; ++p)
      gload16(ga + (size_t)p * 64 * lda + k0, &As[p * 64 + trow][tcol]);
#pragma unroll
    for (int p = 0; p < BN / 64; ++p)
      gload16(gb + (size_t)p * 64 * ldb + k0, &Bs[p * 64 + trow][tcol]);
    __syncthreads();

    h8 a[MF], b[NF];
#pragma unroll
    for (int m = 0; m < MF; ++m)
      a[m] = *(const h8*)&As[wr * WM + m * 16 + fr][fk];
#pragma unroll
    for (int n = 0; n < NF; ++n)
      b[n] = *(const h8*)&Bs[wc * WN + n * 16 + fr][fk];
#pragma unroll
    for (int m = 0; m < MF; ++m)
#pragma unroll
      for (int n = 0; n < NF; ++n)
        acc[m][n] = __builtin_amdgcn_mfma_f32_16x16x32_f16(a[m], b[n], acc[m][n], 0, 0, 0);
    __syncthreads();
  }

  int cr = (lane >> 4) * 4;
  int cc = lane & 15;
#pragma unroll
  for (int m = 0; m < MF; ++m) {
#pragma unroll
    for (int n = 0; n < NF; ++n) {
      int col = bn * BN + wc * WN + n * 16 + cc;
      float bv = ADD_BIAS ? bias[col] : 0.f;
#pragma unroll
      for (int r = 0; r < 4; ++r) {
        int row = bm * BM + wr * WM + m * 16 + cr + r;
        float val = acc[m][n][r] + bv;
        if (OUT_F16) ((_Float16*)Cv)[(size_t)row * ldc + col] = (_Float16)val;
        else         ((float*)Cv)[(size_t)row * ldc + col]    = val;
      }
    }
  }
}

// ---------------- main GEMM: 256x256, 32x32x16 MFMA, pipelined ds_reads ------
// Skeleton (barriers / lgkm(4,8,0) / vmcnt(4) / staging / swizzle) identical to
// the round-3-verified schedule; only fragment shape changed to 32x32x16.
// Per wave: 128x64 output = 4(M) x 2(N) 32x32 tiles, K-tile 64 = 4 k-steps.
// A/B frag: lane holds row=lane&31, k=(lane>>5)*8+j. C/D: col=lane&31,
// row=(reg&3)+8*(reg>>2)+4*(lane>>5)  [m74/m101-verified].
__global__ __launch_bounds__(512, 2) void k_gemm256(
    const _Float16* __restrict__ A,
    const _Float16* __restrict__ B,
    float* __restrict__ C,
    const float* __restrict__ bias) {
  constexpr int LDA = KCAT, LDB = KCAT, LDC = D_OUT;
  constexpr int NT = KCAT / 64;          // 68 (even)
  constexpr int GRID_N = D_OUT / 256;
  __shared__ _Float16 smem[2 * 4 * 8192];   // 131072 B

  int bid = blockIdx.x;
  { int q = gridDim.x >> 3; bid = (bid & 7) * q + (bid >> 3); }  // XCD swizzle
  const int bm = bid / GRID_N, bn = bid % GRID_N;

  const int tid  = threadIdx.x;
  const int lane = tid & 63, wave = tid >> 6;
  const int wr = wave >> 2;          // 0..1  (M half)
  const int wc = wave & 3;           // 0..3  (N quarter)

  const int fr32  = lane & 31;       // fragment row/col
  const int khalf = lane >> 5;       // 0..1  (k 8-elem half within 16)
  const int xorv  = fr32 & 7;

  // staging map: thread -> row tid/8, seg (tid&7)^(row&7); LDS linear tid*16B
  const int srow = tid >> 3;
  const int scol = ((tid & 7) ^ (srow & 7)) * 8;
  const _Float16* gA = A + (size_t)(bm * 256 + srow) * LDA + scol;
  const _Float16* gB = B + (size_t)(bn * 256 + srow) * LDB + scol;

  f16v acc[4][2] = {};               // [mtile][ntile] 32x32 accumulators
  h8 a_lo[2][4], a_hi[2][4];         // [mm][ks]
  h8 b0[4], b1[4];                   // [ks]

  auto stA = [&](int buf, int h, int t) {
    const _Float16* g = gA + (size_t)h * 128 * LDA + t * 64;
    _Float16* l = smem + (buf * 4 + h) * 8192 + tid * 8;
    gload16(g, l);
    gload16(g + (size_t)64 * LDA, l + 4096);
  };
  auto stB = [&](int buf, int h, int t) {
    const _Float16* g = gB + (size_t)h * 128 * LDB + t * 64;
    _Float16* l = smem + (buf * 4 + 2 + h) * 8192 + tid * 8;
    gload16(g, l);
    gload16(g + (size_t)64 * LDB, l + 4096);
  };
  // A: 8 ds_read_b128 (2 mtiles x 4 ks)
  auto rdA = [&](h8 (&dst)[2][4], int buf, int mbase) {
    const _Float16* p = smem + (buf * 4 + wr) * 8192;
#pragma unroll
    for (int mm = 0; mm < 2; ++mm) {
      const _Float16* rp = p + ((mbase + mm) * 32 + fr32) * 64;
#pragma unroll
      for (int ks = 0; ks < 4; ++ks)
        dst[mm][ks] = *(const h8*)(rp + (((ks * 2 + khalf) ^ xorv) << 3));
    }
  };
  // B: 4 ds_read_b128 (1 ntile x 4 ks)
  auto rdB = [&](h8 (&dst)[4], int buf, int nt) {
    const _Float16* rp = smem + (buf * 4 + 2 + (wc >> 1)) * 8192
                       + ((wc & 1) * 64 + nt * 32 + fr32) * 64;
#pragma unroll
    for (int ks = 0; ks < 4; ++ks)
      dst[ks] = *(const h8*)(rp + (((ks * 2 + khalf) ^ xorv) << 3));
  };

#define QUAD(AF, BF, MO, NO)                                                   \
  __builtin_amdgcn_s_setprio(1);                                               \
  _Pragma("unroll")                                                            \
  for (int ks = 0; ks < 4; ++ks)                                               \
    _Pragma("unroll")                                                          \
    for (int mm = 0; mm < 2; ++mm)                                             \
      acc[MO + mm][NO] = __builtin_amdgcn_mfma_f32_32x32x16_f16(               \
          AF[mm][ks], BF[ks], acc[MO + mm][NO], 0, 0, 0);                      \
  __builtin_amdgcn_s_setprio(0);

#define BAR() __builtin_amdgcn_s_barrier()
#define LGKM(N) asm volatile("s_waitcnt lgkmcnt(" #N ")" ::: "memory")
#define VMC(N)  asm volatile("s_waitcnt vmcnt(" #N ")" ::: "memory")

  // ---- prologue: stage t0 fully + t1's B halves ----
  stA(0, 0, 0); stA(0, 1, 0); stB(0, 0, 0); stB(0, 1, 0);
  stB(1, 0, 1); stB(1, 1, 1);
  VMC(4);                      // retire t0's 8 loads; t1-B stays in flight
  BAR();
  rdA(a_lo, 0, 0); rdB(b0, 0, 0);   // tile-0 [A01,B0]

  auto tile = [&](int t, int buf) {
    const int nbuf = buf ^ 1;
    // ---- p1: issue B1; stage (t+1).Ah0; q0 ----
    rdB(b1, buf, 1);
    if (t + 1 < NT) stA(nbuf, 0, t + 1);
    BAR();
    LGKM(4);                   // a_lo,b0 done; b1 may stay out
    QUAD(a_lo, b0, 0, 0);
    BAR();
    // ---- p2: issue A23; stage (t+1).Ah1; q1 ----
    rdA(a_hi, buf, 2);
    if (t + 1 < NT) stA(nbuf, 1, t + 1);
    BAR();
    LGKM(8);                   // b1 done; a_hi may stay out
    QUAD(a_lo, b1, 0, 1);
    BAR();
    // ---- p3: stage (t+2).Bh0; q2 ----
    if (t + 2 < NT) stB(buf, 0, t + 2);
    BAR();
    LGKM(0);                   // a_hi done
    QUAD(a_hi, b0, 2, 0);
    BAR();
    // ---- p4: stage (t+2).Bh1; counted vmcnt; prefetch next [A01,B0]; q3 ----
    if (t + 2 < NT) {
      stB(buf, 1, t + 2);
      VMC(4);                  // retire all of tile t+1's staged data
    } else {
      VMC(0);
    }
    BAR();
    if (t + 1 < NT) { rdA(a_lo, nbuf, 0); rdB(b0, nbuf, 0); }
    QUAD(a_hi, b1, 2, 1);      // operands already waited at q2's lgkm(0)
    BAR();
  };

  for (int tt = 0; tt < NT; tt += 2) {   // NT even: constant buf per call
    tile(tt, 0);
    tile(tt + 1, 1);
  }

  // epilogue: col=lane&31, row=(reg&3)+8*(reg>>2)+4*(lane>>5)
  const int crow = bm * 256 + wr * 128 + (khalf << 2);
  const int ccol = bn * 256 + wc * 64 + fr32;
#pragma unroll
  for (int n = 0; n < 2; ++n) {
    const int col = ccol + n * 32;
    const float bv = bias[col];
#pragma unroll
    for (int m = 0; m < 4; ++m) {
      const int row0 = crow + m * 32;
#pragma unroll
      for (int r = 0; r < 16; ++r) {
        const int row = row0 + (r & 3) + ((r >> 2) << 3);
        C[(size_t)row * LDC + col] = acc[m][n][r] + bv;
      }
    }
  }
#undef QUAD
#undef BAR
#undef LGKM
#undef VMC
}

// ---------------- launch ----------------
extern "C" void kernel_launch(void* const* d_in, const int* in_sizes, int n_in,
                              void* d_out, int out_size, void* d_ws, size_t ws_size,
                              hipStream_t stream) {
  const float* x    = (const float*)d_in[0];
  const int*   qv   = (const int*)d_in[1];
  const float* qs   = (const float*)d_in[2];
  const int*   lv   = (const int*)d_in[3];
  const float* ls   = (const float*)d_in[4];
  const int*   rv   = (const int*)d_in[5];
  const float* rs   = (const float*)d_in[6];
  const float* bias = (const float*)d_in[7];

  int M = in_sizes[0] / D_IN;   // 8192

  char* ws = (char*)d_ws;
  _Float16* Xcat = (_Float16*)ws;                                   // [M][KCAT]
  _Float16* Wcat = (_Float16*)(ws + (size_t)M * KCAT * 2);          // [D_OUT][KCAT]
  _Float16* Rh   = (_Float16*)(ws + (size_t)(M + D_OUT) * KCAT * 2);// [RANK][D_IN]

  k_dequant_q<<<D_OUT * (D_IN / 8) / 256, 256, 0, stream>>>(qv, qs, Wcat);
  k_dequant_l<<<D_OUT * (RANK / 8) / 256, 256, 0, stream>>>(lv, ls, Wcat);
  k_dequant_r<<<RANK * (D_IN / 8) / 256, 256, 0, stream>>>(rv, rs, Rh);
  k_convert_x<<<M * (D_IN / 8) / 256, 256, 0, stream>>>(x, Xcat);

  // xr = Xcat[:, :4096] @ Rh^T  -> f16 into Xcat[:, 4096:4352]
  k_gemm_bt<64, 64, 2, 2, true, false><<<(M / 64) * (RANK / 64), 256, 0, stream>>>(
      Xcat, KCAT, Rh, D_IN, (void*)(Xcat + D_IN), KCAT, nullptr, D_IN, RANK / 64);

  // out = Xcat @ Wcat^T + bias   (K = 4352, 32x32x16 pipelined 256^2 kernel)
  k_gemm256<<<(M / 256) * (D_OUT / 256), 512, 0, stream>>>(
      Xcat, Wcat, (float*)d_out, bias);
}

// Round 6
// 603.770 us; speedup vs baseline: 1.0235x; 1.0235x over previous
//
#include <hip/hip_runtime.h>

#define D_IN  4096
#define D_OUT 4096
#define RANK  256
#define KCAT  (D_IN + RANK)   // 4352

typedef _Float16 h8 __attribute__((ext_vector_type(8)));
typedef float    f4 __attribute__((ext_vector_type(4)));
typedef float    f16v __attribute__((ext_vector_type(16)));

__device__ __forceinline__ void gload16(const void* g, void* l) {
  __builtin_amdgcn_global_load_lds(
      (const __attribute__((address_space(1))) void*)g,
      (__attribute__((address_space(3))) void*)l, 16, 0, 0);
}

__device__ __forceinline__ h8 dq8(int4 v0, int4 v1, float s) {
  h8 h;
  h[0] = (_Float16)((float)v0.x * s);
  h[1] = (_Float16)((float)v0.y * s);
  h[2] = (_Float16)((float)v0.z * s);
  h[3] = (_Float16)((float)v0.w * s);
  h[4] = (_Float16)((float)v1.x * s);
  h[5] = (_Float16)((float)v1.y * s);
  h[6] = (_Float16)((float)v1.z * s);
  h[7] = (_Float16)((float)v1.w * s);
  return h;
}

// ---------------- prologue: dequant + pack (all exact-fit, 16B stores) -------

// q part: W[row][0:4096) ; total threads = D_OUT * 512
__global__ __launch_bounds__(256) void k_dequant_q(
    const int* __restrict__ qv, const float* __restrict__ qs,
    _Float16* __restrict__ W) {
  int i = blockIdx.x * 256 + threadIdx.x;
  int row = i >> 9, c8 = (i & 511) << 3;
  const int* p = qv + (size_t)row * D_IN + c8;
  int4 v0 = *(const int4*)p, v1 = *(const int4*)(p + 4);
  float s = qs[row * (D_IN / 128) + (c8 >> 7)];
  *(h8*)(W + (size_t)row * KCAT + c8) = dq8(v0, v1, s);
}

// l part: W[row][4096:4352) ; total threads = D_OUT * 32
__global__ __launch_bounds__(256) void k_dequant_l(
    const int* __restrict__ lv, const float* __restrict__ ls,
    _Float16* __restrict__ W) {
  int i = blockIdx.x * 256 + threadIdx.x;
  int row = i >> 5, c8 = (i & 31) << 3;
  const int* p = lv + (size_t)row * RANK + c8;
  int4 v0 = *(const int4*)p, v1 = *(const int4*)(p + 4);
  float s = ls[row * (RANK / 128) + (c8 >> 7)];
  *(h8*)(W + (size_t)row * KCAT + D_IN + c8) = dq8(v0, v1, s);
}

// r: total threads = RANK * 512
__global__ __launch_bounds__(256) void k_dequant_r(
    const int* __restrict__ rv, const float* __restrict__ rs,
    _Float16* __restrict__ R) {
  int i = blockIdx.x * 256 + threadIdx.x;
  int row = i >> 9, c8 = (i & 511) << 3;
  const int* p = rv + (size_t)row * D_IN + c8;
  int4 v0 = *(const int4*)p, v1 = *(const int4*)(p + 4);
  float s = rs[row * (D_IN / 128) + (c8 >> 7)];
  *(h8*)(R + (size_t)row * D_IN + c8) = dq8(v0, v1, s);
}

// x f32 -> f16 into Xcat[:, 0:4096) ; total threads = M * 512
__global__ __launch_bounds__(256) void k_convert_x(
    const float* __restrict__ x, _Float16* __restrict__ X) {
  int i = blockIdx.x * 256 + threadIdx.x;
  int row = i >> 9, c8 = (i & 511) << 3;
  const float* p = x + (size_t)row * D_IN + c8;
  f4 v0 = *(const f4*)p, v1 = *(const f4*)(p + 4);
  h8 h;
  h[0] = (_Float16)v0[0]; h[1] = (_Float16)v0[1];
  h[2] = (_Float16)v0[2]; h[3] = (_Float16)v0[3];
  h[4] = (_Float16)v1[0]; h[5] = (_Float16)v1[1];
  h[6] = (_Float16)v1[2]; h[7] = (_Float16)v1[3];
  *(h8*)(X + (size_t)row * KCAT + c8) = h;
}

// ---------------- small GEMM (xr path): m97 structure, 64^2 ----------------
template<int BM, int BN, int MF, int NF, bool OUT_F16, bool ADD_BIAS>
__global__ __launch_bounds__(256) void k_gemm_bt(
    const _Float16* __restrict__ A, int lda,
    const _Float16* __restrict__ B, int ldb,
    void* __restrict__ Cv, int ldc,
    const float* __restrict__ bias,
    int K, int grid_n) {
  constexpr int WM = MF * 16, WN = NF * 16;
  __shared__ _Float16 As[BM][32];
  __shared__ _Float16 Bs[BN][32];

  int bid = blockIdx.x;
  { int q = gridDim.x >> 3; bid = (bid & 7) * q + (bid >> 3); }
  int bm = bid / grid_n, bn = bid % grid_n;

  int tid  = threadIdx.x;
  int lane = tid & 63, wave = tid >> 6;
  int wr = wave >> 1, wc = wave & 1;

  int trow = tid >> 2;
  int tcol = (tid & 3) * 8;
  const _Float16* ga = A + (size_t)(bm * BM + trow) * lda + tcol;
  const _Float16* gb = B + (size_t)(bn * BN + trow) * ldb + tcol;

  f4 acc[MF][NF] = {};

  int fr = lane & 15;
  int fk = (lane >> 4) * 8;

  for (int k0 = 0; k0 < K; k0 += 32) {
#pragma unroll
    for (int p = 0; p < BM / 64; ++p)
      gload16(ga + (size_t)p * 64 * lda + k0, &As[p * 64 + trow][tcol]);
#pragma unroll
    for (int p = 0; p < BN / 64; ++p)
      gload16(gb + (size_t)p * 64 * ldb + k0, &Bs[p * 64 + trow][tcol]);
    __syncthreads();

    h8 a[MF], b[NF];
#pragma unroll
    for (int m = 0; m < MF; ++m)
      a[m] = *(const h8*)&As[wr * WM + m * 16 + fr][fk];
#pragma unroll
    for (int n = 0; n < NF; ++n)
      b[n] = *(const h8*)&Bs[wc * WN + n * 16 + fr][fk];
#pragma unroll
    for (int m = 0; m < MF; ++m)
#pragma unroll
      for (int n = 0; n < NF; ++n)
        acc[m][n] = __builtin_amdgcn_mfma_f32_16x16x32_f16(a[m], b[n], acc[m][n], 0, 0, 0);
    __syncthreads();
  }

  int cr = (lane >> 4) * 4;
  int cc = lane & 15;
#pragma unroll
  for (int m = 0; m < MF; ++m) {
#pragma unroll
    for (int n = 0; n < NF; ++n) {
      int col = bn * BN + wc * WN + n * 16 + cc;
      float bv = ADD_BIAS ? bias[col] : 0.f;
#pragma unroll
      for (int r = 0; r < 4; ++r) {
        int row = bm * BM + wr * WM + m * 16 + cr + r;
        float val = acc[m][n][r] + bv;
        if (OUT_F16) ((_Float16*)Cv)[(size_t)row * ldc + col] = (_Float16)val;
        else         ((float*)Cv)[(size_t)row * ldc + col]    = val;
      }
    }
  }
}

// ---------------- main GEMM: 256x256, 32x32x16 MFMA, pipelined ds_reads ------
// Skeleton (barriers / lgkm(4,8,0) / vmcnt(4) / staging) identical to the
// round-3-verified schedule. Swizzle v2: seg XOR = (row&7) ^ (row_bit4 << 1).
// Rationale: khalf (lane>>5) occupies seg-bit0 of the k-selector; row-bit4
// distinguishes lanes l vs l+16 which otherwise share (khalf, row&7) and
// collide on the same bank group. Putting row-bit4 in seg-bit1 gives the 4
// same-quad lanes (l, l+16, l+32, l+48) 4 distinct segments, like the
// conflict-free 16x16 layout of round 3. Applied on BOTH write (global-source
// pre-swizzle, linear LDS dest) and read (rule 21).
// A/B frag: lane holds row=lane&31, k=(lane>>5)*8+j. C/D: col=lane&31,
// row=(reg&3)+8*(reg>>2)+4*(lane>>5)  [m74/m101-verified].
__global__ __launch_bounds__(512, 2) void k_gemm256(
    const _Float16* __restrict__ A,
    const _Float16* __restrict__ B,
    float* __restrict__ C,
    const float* __restrict__ bias) {
  constexpr int LDA = KCAT, LDB = KCAT, LDC = D_OUT;
  constexpr int NT = KCAT / 64;          // 68 (even)
  constexpr int GRID_N = D_OUT / 256;
  __shared__ _Float16 smem[2 * 4 * 8192];   // 131072 B

  int bid = blockIdx.x;
  { int q = gridDim.x >> 3; bid = (bid & 7) * q + (bid >> 3); }  // XCD swizzle
  const int bm = bid / GRID_N, bn = bid % GRID_N;

  const int tid  = threadIdx.x;
  const int lane = tid & 63, wave = tid >> 6;
  const int wr = wave >> 2;          // 0..1  (M half)
  const int wc = wave & 3;           // 0..3  (N quarter)

  const int fr32  = lane & 31;       // fragment row/col
  const int khalf = lane >> 5;       // 0..1  (k 8-elem half within 16)
  const int xorv  = (fr32 & 7) ^ (((fr32 >> 4) & 1) << 1);   // swizzle v2

  // staging map: thread -> row tid/8, seg (tid&7)^f(row); LDS linear tid*16B
  const int srow = tid >> 3;
  const int scol = (((tid & 7) ^ (srow & 7)) ^ (((srow >> 4) & 1) << 1)) * 8;
  const _Float16* gA = A + (size_t)(bm * 256 + srow) * LDA + scol;
  const _Float16* gB = B + (size_t)(bn * 256 + srow) * LDB + scol;

  f16v acc[4][2] = {};               // [mtile][ntile] 32x32 accumulators
  h8 a_lo[2][4], a_hi[2][4];         // [mm][ks]
  h8 b0[4], b1[4];                   // [ks]

  auto stA = [&](int buf, int h, int t) {
    const _Float16* g = gA + (size_t)h * 128 * LDA + t * 64;
    _Float16* l = smem + (buf * 4 + h) * 8192 + tid * 8;
    gload16(g, l);
    gload16(g + (size_t)64 * LDA, l + 4096);
  };
  auto stB = [&](int buf, int h, int t) {
    const _Float16* g = gB + (size_t)h * 128 * LDB + t * 64;
    _Float16* l = smem + (buf * 4 + 2 + h) * 8192 + tid * 8;
    gload16(g, l);
    gload16(g + (size_t)64 * LDB, l + 4096);
  };
  // A: 8 ds_read_b128 (2 mtiles x 4 ks)
  auto rdA = [&](h8 (&dst)[2][4], int buf, int mbase) {
    const _Float16* p = smem + (buf * 4 + wr) * 8192;
#pragma unroll
    for (int mm = 0; mm < 2; ++mm) {
      const _Float16* rp = p + ((mbase + mm) * 32 + fr32) * 64;
#pragma unroll
      for (int ks = 0; ks < 4; ++ks)
        dst[mm][ks] = *(const h8*)(rp + (((ks * 2 + khalf) ^ xorv) << 3));
    }
  };
  // B: 4 ds_read_b128 (1 ntile x 4 ks)
  auto rdB = [&](h8 (&dst)[4], int buf, int nt) {
    const _Float16* rp = smem + (buf * 4 + 2 + (wc >> 1)) * 8192
                       + ((wc & 1) * 64 + nt * 32 + fr32) * 64;
#pragma unroll
    for (int ks = 0; ks < 4; ++ks)
      dst[ks] = *(const h8*)(rp + (((ks * 2 + khalf) ^ xorv) << 3));
  };

#define QUAD(AF, BF, MO, NO)                                                   \
  __builtin_amdgcn_s_setprio(1);                                               \
  _Pragma("unroll")                                                            \
  for (int ks = 0; ks < 4; ++ks)                                               \
    _Pragma("unroll")                                                          \
    for (int mm = 0; mm < 2; ++mm)                                             \
      acc[MO + mm][NO] = __builtin_amdgcn_mfma_f32_32x32x16_f16(               \
          AF[mm][ks], BF[ks], acc[MO + mm][NO], 0, 0, 0);                      \
  __builtin_amdgcn_s_setprio(0);

#define BAR() __builtin_amdgcn_s_barrier()
#define LGKM(N) asm volatile("s_waitcnt lgkmcnt(" #N ")" ::: "memory")
#define VMC(N)  asm volatile("s_waitcnt vmcnt(" #N ")" ::: "memory")

  // ---- prologue: stage t0 fully + t1's B halves ----
  stA(0, 0, 0); stA(0, 1, 0); stB(0, 0, 0); stB(0, 1, 0);
  stB(1, 0, 1); stB(1, 1, 1);
  VMC(4);                      // retire t0's 8 loads; t1-B stays in flight
  BAR();
  rdA(a_lo, 0, 0); rdB(b0, 0, 0);   // tile-0 [A01,B0]

  auto tile = [&](int t, int buf) {
    const int nbuf = buf ^ 1;
    // ---- p1: issue B1; stage (t+1).Ah0; q0 ----
    rdB(b1, buf, 1);
    if (t + 1 < NT) stA(nbuf, 0, t + 1);
    BAR();
    LGKM(4);                   // a_lo,b0 done; b1 may stay out
    QUAD(a_lo, b0, 0, 0);
    BAR();
    // ---- p2: issue A23; stage (t+1).Ah1; q1 ----
    rdA(a_hi, buf, 2);
    if (t + 1 < NT) stA(nbuf, 1, t + 1);
    BAR();
    LGKM(8);                   // b1 done; a_hi may stay out
    QUAD(a_lo, b1, 0, 1);
    BAR();
    // ---- p3: stage (t+2).Bh0; q2 ----
    if (t + 2 < NT) stB(buf, 0, t + 2);
    BAR();
    LGKM(0);                   // a_hi done
    QUAD(a_hi, b0, 2, 0);
    BAR();
    // ---- p4: stage (t+2).Bh1; counted vmcnt; prefetch next [A01,B0]; q3 ----
    if (t + 2 < NT) {
      stB(buf, 1, t + 2);
      VMC(4);                  // retire all of tile t+1's staged data
    } else {
      VMC(0);
    }
    BAR();
    if (t + 1 < NT) { rdA(a_lo, nbuf, 0); rdB(b0, nbuf, 0); }
    QUAD(a_hi, b1, 2, 1);      // operands already waited at q2's lgkm(0)
    BAR();
  };

  for (int tt = 0; tt < NT; tt += 2) {   // NT even: constant buf per call
    tile(tt, 0);
    tile(tt + 1, 1);
  }

  // epilogue: col=lane&31, row=(reg&3)+8*(reg>>2)+4*(lane>>5)
  const int crow = bm * 256 + wr * 128 + (khalf << 2);
  const int ccol = bn * 256 + wc * 64 + fr32;
#pragma unroll
  for (int n = 0; n < 2; ++n) {
    const int col = ccol + n * 32;
    const float bv = bias[col];
#pragma unroll
    for (int m = 0; m < 4; ++m) {
      const int row0 = crow + m * 32;
#pragma unroll
      for (int r = 0; r < 16; ++r) {
        const int row = row0 + (r & 3) + ((r >> 2) << 3);
        C[(size_t)row * LDC + col] = acc[m][n][r] + bv;
      }
    }
  }
#undef QUAD
#undef BAR
#undef LGKM
#undef VMC
}

// ---------------- launch ----------------
extern "C" void kernel_launch(void* const* d_in, const int* in_sizes, int n_in,
                              void* d_out, int out_size, void* d_ws, size_t ws_size,
                              hipStream_t stream) {
  const float* x    = (const float*)d_in[0];
  const int*   qv   = (const int*)d_in[1];
  const float* qs   = (const float*)d_in[2];
  const int*   lv   = (const int*)d_in[3];
  const float* ls   = (const float*)d_in[4];
  const int*   rv   = (const int*)d_in[5];
  const float* rs   = (const float*)d_in[6];
  const float* bias = (const float*)d_in[7];

  int M = in_sizes[0] / D_IN;   // 8192

  char* ws = (char*)d_ws;
  _Float16* Xcat = (_Float16*)ws;                                   // [M][KCAT]
  _Float16* Wcat = (_Float16*)(ws + (size_t)M * KCAT * 2);          // [D_OUT][KCAT]
  _Float16* Rh   = (_Float16*)(ws + (size_t)(M + D_OUT) * KCAT * 2);// [RANK][D_IN]

  k_dequant_q<<<D_OUT * (D_IN / 8) / 256, 256, 0, stream>>>(qv, qs, Wcat);
  k_dequant_l<<<D_OUT * (RANK / 8) / 256, 256, 0, stream>>>(lv, ls, Wcat);
  k_dequant_r<<<RANK * (D_IN / 8) / 256, 256, 0, stream>>>(rv, rs, Rh);
  k_convert_x<<<M * (D_IN / 8) / 256, 256, 0, stream>>>(x, Xcat);

  // xr = Xcat[:, :4096] @ Rh^T  -> f16 into Xcat[:, 4096:4352]
  k_gemm_bt<64, 64, 2, 2, true, false><<<(M / 64) * (RANK / 64), 256, 0, stream>>>(
      Xcat, KCAT, Rh, D_IN, (void*)(Xcat + D_IN), KCAT, nullptr, D_IN, RANK / 64);

  // out = Xcat @ Wcat^T + bias   (K = 4352, 32x32x16 pipelined 256^2 kernel)
  k_gemm256<<<(M / 256) * (D_OUT / 256), 512, 0, stream>>>(
      Xcat, Wcat, (float*)d_out, bias);
}

// Round 7
// 554.191 us; speedup vs baseline: 1.1150x; 1.0895x over previous
//
#include <hip/hip_runtime.h>

#define D_IN  4096
#define D_OUT 4096
#define RANK  256

typedef _Float16 h8 __attribute__((ext_vector_type(8)));
typedef float    f4 __attribute__((ext_vector_type(4)));

__device__ __forceinline__ void gload16(const void* g, void* l) {
  __builtin_amdgcn_global_load_lds(
      (const __attribute__((address_space(1))) void*)g,
      (__attribute__((address_space(3))) void*)l, 16, 0, 0);
}

__device__ __forceinline__ h8 dq8(int4 v0, int4 v1, float s) {
  h8 h;
  h[0] = (_Float16)((float)v0.x * s);
  h[1] = (_Float16)((float)v0.y * s);
  h[2] = (_Float16)((float)v0.z * s);
  h[3] = (_Float16)((float)v0.w * s);
  h[4] = (_Float16)((float)v1.x * s);
  h[5] = (_Float16)((float)v1.y * s);
  h[6] = (_Float16)((float)v1.z * s);
  h[7] = (_Float16)((float)v1.w * s);
  return h;
}

// ---------------- tiny prologue kernels ----------------

// Lh[4096][256] = dequant(l)  ; threads = 4096*32
__global__ __launch_bounds__(256) void k_dequant_l2(
    const int* __restrict__ lv, const float* __restrict__ ls,
    _Float16* __restrict__ L) {
  int i = blockIdx.x * 256 + threadIdx.x;
  int row = i >> 5, c8 = (i & 31) << 3;
  const int* p = lv + (size_t)row * RANK + c8;
  int4 v0 = *(const int4*)p, v1 = *(const int4*)(p + 4);
  float s = ls[row * (RANK / 128) + (c8 >> 7)];
  *(h8*)(L + (size_t)row * RANK + c8) = dq8(v0, v1, s);
}

// RT[4096][256] = dequant(r)^T ; threads = 4096*32.
// Lanes run consecutive irow -> coalesced reads of rv[k][irow]; the h8 writes
// are 512B-strided (uncoalesced) but the output is only 2 MiB total.
__global__ __launch_bounds__(256) void k_transpose_r(
    const int* __restrict__ rv, const float* __restrict__ rs,
    _Float16* __restrict__ RT) {
  int i = blockIdx.x * 256 + threadIdx.x;
  int c8 = (i >> 12) << 3;          // k base (0,8,..,248)
  int irow = i & 4095;              // output row = r-column
  h8 h;
#pragma unroll
  for (int j = 0; j < 8; ++j) {
    int k = c8 + j;
    float s = rs[k * (D_IN / 128) + (irow >> 7)];
    h[j] = (_Float16)((float)rv[(size_t)k * D_IN + irow] * s);
  }
  *(h8*)(RT + (size_t)irow * RANK + c8) = h;
}

// x f32 -> f16, flat contiguous ; threads = M*512
__global__ __launch_bounds__(256) void k_convert_x(
    const float* __restrict__ x, _Float16* __restrict__ X) {
  int i = blockIdx.x * 256 + threadIdx.x;
  const float* p = x + (size_t)i * 8;
  f4 v0 = *(const f4*)p, v1 = *(const f4*)(p + 4);
  h8 h;
  h[0] = (_Float16)v0[0]; h[1] = (_Float16)v0[1];
  h[2] = (_Float16)v0[2]; h[3] = (_Float16)v0[3];
  h[4] = (_Float16)v1[0]; h[5] = (_Float16)v1[1];
  h[6] = (_Float16)v1[2]; h[7] = (_Float16)v1[3];
  *(h8*)(X + (size_t)i * 8) = h;
}

// ---------------- Wfull = dequant(q) + Lh @ RT^T  (64^2 m97 tile, K=256) ----
// C[o][i] = sum_k Lh[o][k]*RT[i][k] + qv[o][i]*qs[o][i/128], stored f16.
__global__ __launch_bounds__(256) void k_wfull(
    const _Float16* __restrict__ A,   // Lh [4096][256]
    const _Float16* __restrict__ B,   // RT [4096][256]
    const int* __restrict__ qv, const float* __restrict__ qs,
    _Float16* __restrict__ W) {       // [4096][4096]
  __shared__ _Float16 As[64][32];
  __shared__ _Float16 Bs[64][32];

  int bid = blockIdx.x;
  { int q = gridDim.x >> 3; bid = (bid & 7) * q + (bid >> 3); }
  int bm = bid >> 6, bn = bid & 63;

  int tid  = threadIdx.x;
  int lane = tid & 63, wave = tid >> 6;
  int wr = wave >> 1, wc = wave & 1;

  int trow = tid >> 2;
  int tcol = (tid & 3) * 8;
  const _Float16* ga = A + (size_t)(bm * 64 + trow) * RANK + tcol;
  const _Float16* gb = B + (size_t)(bn * 64 + trow) * RANK + tcol;

  f4 acc[2][2] = {};
  int fr = lane & 15;
  int fk = (lane >> 4) * 8;

  for (int k0 = 0; k0 < RANK; k0 += 32) {
    gload16(ga + k0, &As[trow][tcol]);
    gload16(gb + k0, &Bs[trow][tcol]);
    __syncthreads();
    h8 a[2], b[2];
#pragma unroll
    for (int m = 0; m < 2; ++m)
      a[m] = *(const h8*)&As[wr * 32 + m * 16 + fr][fk];
#pragma unroll
    for (int n = 0; n < 2; ++n)
      b[n] = *(const h8*)&Bs[wc * 32 + n * 16 + fr][fk];
#pragma unroll
    for (int m = 0; m < 2; ++m)
#pragma unroll
      for (int n = 0; n < 2; ++n)
        acc[m][n] = __builtin_amdgcn_mfma_f32_16x16x32_f16(a[m], b[n], acc[m][n], 0, 0, 0);
    __syncthreads();
  }

  int cr = (lane >> 4) * 4;
  int cc = lane & 15;
#pragma unroll
  for (int m = 0; m < 2; ++m)
#pragma unroll
    for (int n = 0; n < 2; ++n) {
      int col = bn * 64 + wc * 32 + n * 16 + cc;
#pragma unroll
      for (int r = 0; r < 4; ++r) {
        int row = bm * 64 + wr * 32 + m * 16 + cr + r;
        float qd = (float)qv[(size_t)row * D_IN + col]
                 * qs[row * (D_IN / 128) + (col >> 7)];
        W[(size_t)row * D_IN + col] = (_Float16)(acc[m][n][r] + qd);
      }
    }
}

// ---------------- main GEMM: round-3-verified 256x256 16x16x32, K=4096 ------
// C[M][N] = A[M][4096] * B[N][4096]^T + bias.  BK=64, 8 waves (2Mx4N),
// 128 KiB LDS, pipelined ds_reads with counted lgkm, vmcnt(4)/tile.
// (Byte-identical to the 268us round-3 kernel except K: 4352 -> 4096.)
__global__ __launch_bounds__(512, 2) void k_gemm256(
    const _Float16* __restrict__ A,
    const _Float16* __restrict__ B,
    float* __restrict__ C,
    const float* __restrict__ bias) {
  constexpr int LDA = D_IN, LDB = D_IN, LDC = D_OUT;
  constexpr int NT = D_IN / 64;          // 64 (even)
  constexpr int GRID_N = D_OUT / 256;
  __shared__ _Float16 smem[2 * 4 * 8192];   // 131072 B

  int bid = blockIdx.x;
  { int q = gridDim.x >> 3; bid = (bid & 7) * q + (bid >> 3); }  // XCD swizzle
  const int bm = bid / GRID_N, bn = bid % GRID_N;

  const int tid  = threadIdx.x;
  const int lane = tid & 63, wave = tid >> 6;
  const int wr = wave >> 2;          // 0..1  (M half)
  const int wc = wave & 3;           // 0..3  (N quarter)

  const int fr   = lane & 15;        // fragment row
  const int kgrp = lane >> 4;        // 0..3
  const int xorv = fr & 7;
  const int seg0 = ((0 | kgrp) ^ xorv) * 8;
  const int seg1 = ((4 | kgrp) ^ xorv) * 8;

  // staging map: thread -> row tid/8, seg (tid&7)^(row&7); LDS linear tid*16B
  const int srow = tid >> 3;
  const int scol = ((tid & 7) ^ (srow & 7)) * 8;
  const _Float16* gA = A + (size_t)(bm * 256 + srow) * LDA + scol;
  const _Float16* gB = B + (size_t)(bn * 256 + srow) * LDB + scol;

  f4 acc[8][4] = {};
  h8 a_lo[4][2], a_hi[4][2], b01[2][2], b23[2][2];

  auto stA = [&](int buf, int h, int t) {
    const _Float16* g = gA + (size_t)h * 128 * LDA + t * 64;
    _Float16* l = smem + (buf * 4 + h) * 8192 + tid * 8;
    gload16(g, l);
    gload16(g + (size_t)64 * LDA, l + 4096);
  };
  auto stB = [&](int buf, int h, int t) {
    const _Float16* g = gB + (size_t)h * 128 * LDB + t * 64;
    _Float16* l = smem + (buf * 4 + 2 + h) * 8192 + tid * 8;
    gload16(g, l);
    gload16(g + (size_t)64 * LDB, l + 4096);
  };
  auto rdA = [&](h8 (&dst)[4][2], int buf, int mbase) {
    const _Float16* p = smem + (buf * 4 + wr) * 8192 + fr * 64;
#pragma unroll
    for (int mm = 0; mm < 4; ++mm) {
      dst[mm][0] = *(const h8*)(p + (mbase + mm) * 1024 + seg0);
      dst[mm][1] = *(const h8*)(p + (mbase + mm) * 1024 + seg1);
    }
  };
  auto rdB = [&](h8 (&dst)[2][2], int buf, int nbase) {
    const _Float16* p = smem + (buf * 4 + 2 + (wc >> 1)) * 8192
                      + ((wc & 1) * 64 + fr) * 64;
#pragma unroll
    for (int nn = 0; nn < 2; ++nn) {
      dst[nn][0] = *(const h8*)(p + (nbase + nn) * 1024 + seg0);
      dst[nn][1] = *(const h8*)(p + (nbase + nn) * 1024 + seg1);
    }
  };

#define QUAD(AF, BF, MO, NO)                                                   \
  __builtin_amdgcn_s_setprio(1);                                               \
  _Pragma("unroll")                                                            \
  for (int mm = 0; mm < 4; ++mm)                                               \
    _Pragma("unroll")                                                          \
    for (int nn = 0; nn < 2; ++nn) {                                           \
      acc[MO + mm][NO + nn] = __builtin_amdgcn_mfma_f32_16x16x32_f16(          \
          AF[mm][0], BF[nn][0], acc[MO + mm][NO + nn], 0, 0, 0);               \
      acc[MO + mm][NO + nn] = __builtin_amdgcn_mfma_f32_16x16x32_f16(          \
          AF[mm][1], BF[nn][1], acc[MO + mm][NO + nn], 0, 0, 0);               \
    }                                                                          \
  __builtin_amdgcn_s_setprio(0);

#define BAR() __builtin_amdgcn_s_barrier()
#define LGKM(N) asm volatile("s_waitcnt lgkmcnt(" #N ")" ::: "memory")
#define VMC(N)  asm volatile("s_waitcnt vmcnt(" #N ")" ::: "memory")

  // ---- prologue: stage t0 fully + t1's B halves ----
  stA(0, 0, 0); stA(0, 1, 0); stB(0, 0, 0); stB(0, 1, 0);
  stB(1, 0, 1); stB(1, 1, 1);
  VMC(4);                      // retire t0's 8 loads; t1-B stays in flight
  BAR();
  rdA(a_lo, 0, 0); rdB(b01, 0, 0);   // tile-0 [A03,B01]

  auto tile = [&](int t, int buf) {
    const int nbuf = buf ^ 1;
    // ---- p1: issue B23; stage (t+1).Ah0; q0 ----
    rdB(b23, buf, 2);
    if (t + 1 < NT) stA(nbuf, 0, t + 1);
    BAR();
    LGKM(4);                   // A03,B01 done; B23 may stay out
    QUAD(a_lo, b01, 0, 0);
    BAR();
    // ---- p2: issue A47; stage (t+1).Ah1; q1 ----
    rdA(a_hi, buf, 4);
    if (t + 1 < NT) stA(nbuf, 1, t + 1);
    BAR();
    LGKM(8);                   // B23 done; A47 may stay out
    QUAD(a_lo, b23, 0, 2);
    BAR();
    // ---- p3: stage (t+2).Bh0; q2 ----
    if (t + 2 < NT) stB(buf, 0, t + 2);
    BAR();
    LGKM(0);                   // A47 done
    QUAD(a_hi, b01, 4, 0);
    BAR();
    // ---- p4: stage (t+2).Bh1; counted vmcnt; prefetch next [A03,B01]; q3 ----
    if (t + 2 < NT) {
      stB(buf, 1, t + 2);
      VMC(4);                  // retire all of tile t+1's staged data
    } else {
      VMC(0);
    }
    BAR();
    if (t + 1 < NT) { rdA(a_lo, nbuf, 0); rdB(b01, nbuf, 0); }
    QUAD(a_hi, b23, 4, 2);     // operands already waited at q2's lgkm(0)
    BAR();
  };

  for (int tt = 0; tt < NT; tt += 2) {   // NT even: constant buf per call
    tile(tt, 0);
    tile(tt + 1, 1);
  }

  // epilogue: C/D layout col=lane&15, row=(lane>>4)*4+reg
  const int crow = bm * 256 + wr * 128 + kgrp * 4;
  const int ccol = bn * 256 + wc * 64 + fr;
#pragma unroll
  for (int n = 0; n < 4; ++n) {
    const int col = ccol + n * 16;
    const float bv = bias[col];
#pragma unroll
    for (int m = 0; m < 8; ++m) {
      const int row0 = crow + m * 16;
#pragma unroll
      for (int r = 0; r < 4; ++r)
        C[(size_t)(row0 + r) * LDC + col] = acc[m][n][r] + bv;
    }
  }
#undef QUAD
#undef BAR
#undef LGKM
#undef VMC
}

// ---------------- launch ----------------
extern "C" void kernel_launch(void* const* d_in, const int* in_sizes, int n_in,
                              void* d_out, int out_size, void* d_ws, size_t ws_size,
                              hipStream_t stream) {
  const float* x    = (const float*)d_in[0];
  const int*   qv   = (const int*)d_in[1];
  const float* qs   = (const float*)d_in[2];
  const int*   lv   = (const int*)d_in[3];
  const float* ls   = (const float*)d_in[4];
  const int*   rv   = (const int*)d_in[5];
  const float* rs   = (const float*)d_in[6];
  const float* bias = (const float*)d_in[7];

  int M = in_sizes[0] / D_IN;   // 8192

  char* ws = (char*)d_ws;
  _Float16* Xh = (_Float16*)ws;                                 // [M][4096]   64 MiB
  _Float16* Wf = (_Float16*)(ws + (size_t)M * D_IN * 2);        // [4096][4096] 32 MiB
  _Float16* Lh = Wf + (size_t)D_OUT * D_IN;                     // [4096][256]  2 MiB
  _Float16* RT = Lh + (size_t)D_OUT * RANK;                     // [4096][256]  2 MiB

  k_dequant_l2<<<D_OUT * (RANK / 8) / 256, 256, 0, stream>>>(lv, ls, Lh);
  k_transpose_r<<<D_IN * (RANK / 8) / 256, 256, 0, stream>>>(rv, rs, RT);
  k_convert_x<<<M * (D_IN / 8) / 256, 256, 0, stream>>>(x, Xh);

  // Wfull = dequant(q) + Lh @ RT^T   (f16 [4096][4096])
  k_wfull<<<(D_OUT / 64) * (D_IN / 64), 256, 0, stream>>>(Lh, RT, qv, qs, Wf);

  // out = Xh @ Wfull^T + bias   (K = 4096, round-3-verified pipelined kernel)
  k_gemm256<<<(M / 256) * (D_OUT / 256), 512, 0, stream>>>(
      Xh, Wf, (float*)d_out, bias);
}

// Round 8
// 534.991 us; speedup vs baseline: 1.1551x; 1.0359x over previous
//
#include <hip/hip_runtime.h>

#define D_IN  4096
#define D_OUT 4096
#define RANK  256

typedef _Float16 h8 __attribute__((ext_vector_type(8)));
typedef float    f4 __attribute__((ext_vector_type(4)));

__device__ __forceinline__ void gload16(const void* g, void* l) {
  __builtin_amdgcn_global_load_lds(
      (const __attribute__((address_space(1))) void*)g,
      (__attribute__((address_space(3))) void*)l, 16, 0, 0);
}

__device__ __forceinline__ h8 dq8(int4 v0, int4 v1, float s) {
  h8 h;
  h[0] = (_Float16)((float)v0.x * s);
  h[1] = (_Float16)((float)v0.y * s);
  h[2] = (_Float16)((float)v0.z * s);
  h[3] = (_Float16)((float)v0.w * s);
  h[4] = (_Float16)((float)v1.x * s);
  h[5] = (_Float16)((float)v1.y * s);
  h[6] = (_Float16)((float)v1.z * s);
  h[7] = (_Float16)((float)v1.w * s);
  return h;
}

// ---------------- tiny prologue kernels ----------------

// Lh[4096][256] = dequant(l)  ; threads = 4096*32
__global__ __launch_bounds__(256) void k_dequant_l2(
    const int* __restrict__ lv, const float* __restrict__ ls,
    _Float16* __restrict__ L) {
  int i = blockIdx.x * 256 + threadIdx.x;
  int row = i >> 5, c8 = (i & 31) << 3;
  const int* p = lv + (size_t)row * RANK + c8;
  int4 v0 = *(const int4*)p, v1 = *(const int4*)(p + 4);
  float s = ls[row * (RANK / 128) + (c8 >> 7)];
  *(h8*)(L + (size_t)row * RANK + c8) = dq8(v0, v1, s);
}

// RT[4096][256] = dequant(r)^T ; threads = 4096*32.
__global__ __launch_bounds__(256) void k_transpose_r(
    const int* __restrict__ rv, const float* __restrict__ rs,
    _Float16* __restrict__ RT) {
  int i = blockIdx.x * 256 + threadIdx.x;
  int c8 = (i >> 12) << 3;          // k base (0,8,..,248)
  int irow = i & 4095;              // output row = r-column
  h8 h;
#pragma unroll
  for (int j = 0; j < 8; ++j) {
    int k = c8 + j;
    float s = rs[k * (D_IN / 128) + (irow >> 7)];
    h[j] = (_Float16)((float)rv[(size_t)k * D_IN + irow] * s);
  }
  *(h8*)(RT + (size_t)irow * RANK + c8) = h;
}

// x f32 -> f16, flat contiguous ; threads = M*512
__global__ __launch_bounds__(256) void k_convert_x(
    const float* __restrict__ x, _Float16* __restrict__ X) {
  int i = blockIdx.x * 256 + threadIdx.x;
  const float* p = x + (size_t)i * 8;
  f4 v0 = *(const f4*)p, v1 = *(const f4*)(p + 4);
  h8 h;
  h[0] = (_Float16)v0[0]; h[1] = (_Float16)v0[1];
  h[2] = (_Float16)v0[2]; h[3] = (_Float16)v0[3];
  h[4] = (_Float16)v1[0]; h[5] = (_Float16)v1[1];
  h[6] = (_Float16)v1[2]; h[7] = (_Float16)v1[3];
  *(h8*)(X + (size_t)i * 8) = h;
}

// ---------------- Wfull = dequant(q) + Lh @ RT^T  (64^2 m97 tile, K=256) ----
// Epilogue v2: stage low-rank f32 into LDS (pitch 68, bank-spread), then a
// row-linear vectorized pass: int4 qv loads + h8 stores (pure row/col math).
__global__ __launch_bounds__(256) void k_wfull(
    const _Float16* __restrict__ A,   // Lh [4096][256]
    const _Float16* __restrict__ B,   // RT [4096][256]
    const int* __restrict__ qv, const float* __restrict__ qs,
    _Float16* __restrict__ W) {       // [4096][4096]
  __shared__ _Float16 As[64][32];
  __shared__ _Float16 Bs[64][32];
  __shared__ float eps[64][68];       // pitch 68: rows spread banks by 4

  int bid = blockIdx.x;
  { int q = gridDim.x >> 3; bid = (bid & 7) * q + (bid >> 3); }
  int bm = bid >> 6, bn = bid & 63;

  int tid  = threadIdx.x;
  int lane = tid & 63, wave = tid >> 6;
  int wr = wave >> 1, wc = wave & 1;

  int trow = tid >> 2;
  int tcol = (tid & 3) * 8;
  const _Float16* ga = A + (size_t)(bm * 64 + trow) * RANK + tcol;
  const _Float16* gb = B + (size_t)(bn * 64 + trow) * RANK + tcol;

  f4 acc[2][2] = {};
  int fr = lane & 15;
  int fk = (lane >> 4) * 8;

  for (int k0 = 0; k0 < RANK; k0 += 32) {
    gload16(ga + k0, &As[trow][tcol]);
    gload16(gb + k0, &Bs[trow][tcol]);
    __syncthreads();
    h8 a[2], b[2];
#pragma unroll
    for (int m = 0; m < 2; ++m)
      a[m] = *(const h8*)&As[wr * 32 + m * 16 + fr][fk];
#pragma unroll
    for (int n = 0; n < 2; ++n)
      b[n] = *(const h8*)&Bs[wc * 32 + n * 16 + fr][fk];
#pragma unroll
    for (int m = 0; m < 2; ++m)
#pragma unroll
      for (int n = 0; n < 2; ++n)
        acc[m][n] = __builtin_amdgcn_mfma_f32_16x16x32_f16(a[m], b[n], acc[m][n], 0, 0, 0);
    __syncthreads();
  }

  // stage low-rank result to LDS (C/D layout: col=lane&15, row=(lane>>4)*4+r)
  int cr = (lane >> 4) * 4;
  int cc = lane & 15;
#pragma unroll
  for (int m = 0; m < 2; ++m)
#pragma unroll
    for (int n = 0; n < 2; ++n)
#pragma unroll
      for (int r = 0; r < 4; ++r)
        eps[wr * 32 + m * 16 + cr + r][wc * 32 + n * 16 + cc] = acc[m][n][r];
  __syncthreads();

  // vectorized dequant-add pass: thread -> row tid/4, 16 cols at (tid%4)*16
  int row = tid >> 2, c0 = (tid & 3) * 16;
  size_t gbase = (size_t)(bm * 64 + row) * D_IN + bn * 64 + c0;
  float s = qs[(bm * 64 + row) * (D_IN / 128) + ((bn * 64 + c0) >> 7)];
#pragma unroll
  for (int u = 0; u < 2; ++u) {
    const int* qp = qv + gbase + u * 8;
    int4 q0 = *(const int4*)qp, q1 = *(const int4*)(qp + 4);
    f4 l0 = *(const f4*)&eps[row][c0 + u * 8];
    f4 l1 = *(const f4*)&eps[row][c0 + u * 8 + 4];
    h8 o;
    o[0] = (_Float16)((float)q0.x * s + l0[0]);
    o[1] = (_Float16)((float)q0.y * s + l0[1]);
    o[2] = (_Float16)((float)q0.z * s + l0[2]);
    o[3] = (_Float16)((float)q0.w * s + l0[3]);
    o[4] = (_Float16)((float)q1.x * s + l1[0]);
    o[5] = (_Float16)((float)q1.y * s + l1[1]);
    o[6] = (_Float16)((float)q1.z * s + l1[2]);
    o[7] = (_Float16)((float)q1.w * s + l1[3]);
    *(h8*)(W + gbase + u * 8) = o;
  }
}

// ---------------- main GEMM: round-3-verified 256x256 16x16x32, K=4096 ------
// C[M][N] = A[M][4096] * B[N][4096]^T + bias.  BK=64, 8 waves (2Mx4N),
// 128 KiB LDS, pipelined ds_reads with counted lgkm, vmcnt(4)/tile.
// K-loop byte-identical to round 7 (255us, 0 conflicts). Epilogue v2:
// wave-private LDS transpose (pitch 68) -> global_store_dwordx4, 256B segments.
__global__ __launch_bounds__(512, 2) void k_gemm256(
    const _Float16* __restrict__ A,
    const _Float16* __restrict__ B,
    float* __restrict__ C,
    const float* __restrict__ bias) {
  constexpr int LDA = D_IN, LDB = D_IN, LDC = D_OUT;
  constexpr int NT = D_IN / 64;          // 64 (even)
  constexpr int GRID_N = D_OUT / 256;
  __shared__ _Float16 smem[2 * 4 * 8192];   // 131072 B

  int bid = blockIdx.x;
  { int q = gridDim.x >> 3; bid = (bid & 7) * q + (bid >> 3); }  // XCD swizzle
  const int bm = bid / GRID_N, bn = bid % GRID_N;

  const int tid  = threadIdx.x;
  const int lane = tid & 63, wave = tid >> 6;
  const int wr = wave >> 2;          // 0..1  (M half)
  const int wc = wave & 3;           // 0..3  (N quarter)

  const int fr   = lane & 15;        // fragment row
  const int kgrp = lane >> 4;        // 0..3
  const int xorv = fr & 7;
  const int seg0 = ((0 | kgrp) ^ xorv) * 8;
  const int seg1 = ((4 | kgrp) ^ xorv) * 8;

  // staging map: thread -> row tid/8, seg (tid&7)^(row&7); LDS linear tid*16B
  const int srow = tid >> 3;
  const int scol = ((tid & 7) ^ (srow & 7)) * 8;
  const _Float16* gA = A + (size_t)(bm * 256 + srow) * LDA + scol;
  const _Float16* gB = B + (size_t)(bn * 256 + srow) * LDB + scol;

  f4 acc[8][4] = {};
  h8 a_lo[4][2], a_hi[4][2], b01[2][2], b23[2][2];

  auto stA = [&](int buf, int h, int t) {
    const _Float16* g = gA + (size_t)h * 128 * LDA + t * 64;
    _Float16* l = smem + (buf * 4 + h) * 8192 + tid * 8;
    gload16(g, l);
    gload16(g + (size_t)64 * LDA, l + 4096);
  };
  auto stB = [&](int buf, int h, int t) {
    const _Float16* g = gB + (size_t)h * 128 * LDB + t * 64;
    _Float16* l = smem + (buf * 4 + 2 + h) * 8192 + tid * 8;
    gload16(g, l);
    gload16(g + (size_t)64 * LDB, l + 4096);
  };
  auto rdA = [&](h8 (&dst)[4][2], int buf, int mbase) {
    const _Float16* p = smem + (buf * 4 + wr) * 8192 + fr * 64;
#pragma unroll
    for (int mm = 0; mm < 4; ++mm) {
      dst[mm][0] = *(const h8*)(p + (mbase + mm) * 1024 + seg0);
      dst[mm][1] = *(const h8*)(p + (mbase + mm) * 1024 + seg1);
    }
  };
  auto rdB = [&](h8 (&dst)[2][2], int buf, int nbase) {
    const _Float16* p = smem + (buf * 4 + 2 + (wc >> 1)) * 8192
                      + ((wc & 1) * 64 + fr) * 64;
#pragma unroll
    for (int nn = 0; nn < 2; ++nn) {
      dst[nn][0] = *(const h8*)(p + (nbase + nn) * 1024 + seg0);
      dst[nn][1] = *(const h8*)(p + (nbase + nn) * 1024 + seg1);
    }
  };

#define QUAD(AF, BF, MO, NO)                                                   \
  __builtin_amdgcn_s_setprio(1);                                               \
  _Pragma("unroll")                                                            \
  for (int mm = 0; mm < 4; ++mm)                                               \
    _Pragma("unroll")                                                          \
    for (int nn = 0; nn < 2; ++nn) {                                           \
      acc[MO + mm][NO + nn] = __builtin_amdgcn_mfma_f32_16x16x32_f16(          \
          AF[mm][0], BF[nn][0], acc[MO + mm][NO + nn], 0, 0, 0);               \
      acc[MO + mm][NO + nn] = __builtin_amdgcn_mfma_f32_16x16x32_f16(          \
          AF[mm][1], BF[nn][1], acc[MO + mm][NO + nn], 0, 0, 0);               \
    }                                                                          \
  __builtin_amdgcn_s_setprio(0);

#define BAR() __builtin_amdgcn_s_barrier()
#define LGKM(N) asm volatile("s_waitcnt lgkmcnt(" #N ")" ::: "memory")
#define VMC(N)  asm volatile("s_waitcnt vmcnt(" #N ")" ::: "memory")

  // ---- prologue: stage t0 fully + t1's B halves ----
  stA(0, 0, 0); stA(0, 1, 0); stB(0, 0, 0); stB(0, 1, 0);
  stB(1, 0, 1); stB(1, 1, 1);
  VMC(4);                      // retire t0's 8 loads; t1-B stays in flight
  BAR();
  rdA(a_lo, 0, 0); rdB(b01, 0, 0);   // tile-0 [A03,B01]

  auto tile = [&](int t, int buf) {
    const int nbuf = buf ^ 1;
    // ---- p1: issue B23; stage (t+1).Ah0; q0 ----
    rdB(b23, buf, 2);
    if (t + 1 < NT) stA(nbuf, 0, t + 1);
    BAR();
    LGKM(4);                   // A03,B01 done; B23 may stay out
    QUAD(a_lo, b01, 0, 0);
    BAR();
    // ---- p2: issue A47; stage (t+1).Ah1; q1 ----
    rdA(a_hi, buf, 4);
    if (t + 1 < NT) stA(nbuf, 1, t + 1);
    BAR();
    LGKM(8);                   // B23 done; A47 may stay out
    QUAD(a_lo, b23, 0, 2);
    BAR();
    // ---- p3: stage (t+2).Bh0; q2 ----
    if (t + 2 < NT) stB(buf, 0, t + 2);
    BAR();
    LGKM(0);                   // A47 done
    QUAD(a_hi, b01, 4, 0);
    BAR();
    // ---- p4: stage (t+2).Bh1; counted vmcnt; prefetch next [A03,B01]; q3 ----
    if (t + 2 < NT) {
      stB(buf, 1, t + 2);
      VMC(4);                  // retire all of tile t+1's staged data
    } else {
      VMC(0);
    }
    BAR();
    if (t + 1 < NT) { rdA(a_lo, nbuf, 0); rdB(b01, nbuf, 0); }
    QUAD(a_hi, b23, 4, 2);     // operands already waited at q2's lgkm(0)
    BAR();
  };

  for (int tt = 0; tt < NT; tt += 2) {   // NT even: constant buf per call
    tile(tt, 0);
    tile(tt + 1, 1);
  }

  // ---- epilogue v2: wave-private LDS transpose, 16B coalesced stores ----
  // write: (row16 = kgrp*4+r, col64 = n*16+fr) at pitch 68 (2-way banks, free)
  // read:  row16 = j*4+kgrp, 16 lanes cover one row -> 256B contiguous stores
  float* wbuf = (float*)smem + wave * 1088;     // 16*68 floats per wave
  float bv[4];
#pragma unroll
  for (int n = 0; n < 4; ++n)
    bv[n] = bias[bn * 256 + wc * 64 + n * 16 + fr];
  const int crow0 = bm * 256 + wr * 128;
  const int gcol0 = bn * 256 + wc * 64 + fr * 4;   // note: fr*4 read-side cols
#pragma unroll
  for (int m = 0; m < 8; ++m) {
#pragma unroll
    for (int n = 0; n < 4; ++n)
#pragma unroll
      for (int r = 0; r < 4; ++r)
        wbuf[(kgrp * 4 + r) * 68 + n * 16 + fr] = acc[m][n][r] + bv[n];
    LGKM(0);                    // wave-private: no barrier needed
#pragma unroll
    for (int j = 0; j < 4; ++j) {
      int r16 = j * 4 + kgrp;
      f4 v = *(const f4*)&wbuf[r16 * 68 + fr * 4];
      *(f4*)&C[(size_t)(crow0 + m * 16 + r16) * LDC + gcol0] = v;
    }
    LGKM(0);                    // reads done before next m overwrites wbuf
  }
#undef QUAD
#undef BAR
#undef LGKM
#undef VMC
}

// ---------------- launch ----------------
extern "C" void kernel_launch(void* const* d_in, const int* in_sizes, int n_in,
                              void* d_out, int out_size, void* d_ws, size_t ws_size,
                              hipStream_t stream) {
  const float* x    = (const float*)d_in[0];
  const int*   qv   = (const int*)d_in[1];
  const float* qs   = (const float*)d_in[2];
  const int*   lv   = (const int*)d_in[3];
  const float* ls   = (const float*)d_in[4];
  const int*   rv   = (const int*)d_in[5];
  const float* rs   = (const float*)d_in[6];
  const float* bias = (const float*)d_in[7];

  int M = in_sizes[0] / D_IN;   // 8192

  char* ws = (char*)d_ws;
  _Float16* Xh = (_Float16*)ws;                                 // [M][4096]   64 MiB
  _Float16* Wf = (_Float16*)(ws + (size_t)M * D_IN * 2);        // [4096][4096] 32 MiB
  _Float16* Lh = Wf + (size_t)D_OUT * D_IN;                     // [4096][256]  2 MiB
  _Float16* RT = Lh + (size_t)D_OUT * RANK;                     // [4096][256]  2 MiB

  k_dequant_l2<<<D_OUT * (RANK / 8) / 256, 256, 0, stream>>>(lv, ls, Lh);
  k_transpose_r<<<D_IN * (RANK / 8) / 256, 256, 0, stream>>>(rv, rs, RT);
  k_convert_x<<<M * (D_IN / 8) / 256, 256, 0, stream>>>(x, Xh);

  // Wfull = dequant(q) + Lh @ RT^T   (f16 [4096][4096])
  k_wfull<<<(D_OUT / 64) * (D_IN / 64), 256, 0, stream>>>(Lh, RT, qv, qs, Wf);

  // out = Xh @ Wfull^T + bias   (K = 4096, pipelined kernel, epilogue v2)
  k_gemm256<<<(M / 256) * (D_OUT / 256), 512, 0, stream>>>(
      Xh, Wf, (float*)d_out, bias);
}